// Round 11
// baseline (1369.874 us; speedup 1.0000x reference)
//
#include <hip/hip_runtime.h>
#include <hip/hip_bf16.h>

// Problem constants (fixed by setup_inputs)
#define N_ 4
#define M_ 64
#define C_ 768
#define HF 48
#define WF 48
#define HWF (HF*WF)   // 2304
#define HI 768
#define WI 768
#define R_ 8
#define NM (N_*M_)

// ws layout:
//   [0)        uint bbox[NM][4]  (ymin'=max(768-y), ymax'=max(y+1),
//                                 xmin'=max(768-x), xmax'=max(x+1); empty <=> ymax'==0)
//   [4096)     uint8 masks_small[NM][48*48]
//   [593920)   uint cnt[NM]      per-map block-completion counters
//   [1<<20)    float4  wm4[NM*64]  bilinear weights * crop-mask   256 KB
//   [+256K)    ushort4 a4[NM*64]   corner hw-indices              128 KB
// One hipMemsetAsync(0) over [0, WS_ZERO_BYTES) initializes bbox+msmall+cnt.
#define WS_BBOX_OFF   0
#define WS_MS_OFF     4096
#define MS_PER_MAP    (HF*WF)   // 2304
#define WS_CNT_OFF    (WS_MS_OFF + NM*MS_PER_MAP)     // 593920
#define WS_ZERO_BYTES (WS_CNT_OFF + NM*4)             // 594944
#define WS_W4_OFF     (1u<<20)
#define WS_A4_OFF     (WS_W4_OFF + NM*64*16)

#define VEC4_PER_MAP  (HI*WI/4)                       // 147456
#define SCAN_LPT      16                              // float4 NT loads/thread
#define SCAN_BX       (VEC4_PER_MAP/(256*SCAN_LPT))   // 36

typedef float f32x4 __attribute__((ext_vector_type(4)));
typedef unsigned int u32;

// Phase 1: stream the 604MB mask tensor once (r6/r8 known-good hot loop:
// nontemporal float4, LPT=16, interleaved test — 5 variants all pinned at
// ~5.4 TB/s, so this is the empirical read ceiling).
// window(15) < stride(16) => each nonzero pixel maps to at most one
// masks_small cell: i=(y+7)>>4, valid iff (y&15)!=8 && i<48.
//
// r11 fusion: per-map completion counter; the LAST of the 36 blocks for a
// map runs the weights body for that map (boxes out0, roi_masks out1,
// wm4/a4 tables). Ordering: every block __threadfence()s (drain stores +
// atomics to L2, invalidate L1) before its counter increment; the winner
// __threadfence()s after observing completion (acquire) before reading
// bbox/msmall. All cross-block traffic is L2-device-scope.
__global__ void scan_weights_kernel(const f32x4* __restrict__ masks,
                                    u32* __restrict__ bbox,
                                    unsigned char* __restrict__ msmall,
                                    u32* __restrict__ cnt,
                                    float4* __restrict__ wm4,
                                    ushort4* __restrict__ a4,
                                    float* __restrict__ out) {
    const int nm = blockIdx.y;
    const size_t map_off = (size_t)nm * VEC4_PER_MAP;
    const int chunk = blockIdx.x * (256 * SCAN_LPT);
    u32* bb = bbox + nm * 4;
    unsigned char* ms = msmall + nm * MS_PER_MAP;

    #pragma unroll
    for (int k = 0; k < SCAN_LPT; ++k) {
        const int t = chunk + k * 256 + threadIdx.x;
        const f32x4 v = __builtin_nontemporal_load(masks + map_off + t);
        if (v.x > 0.f || v.y > 0.f || v.z > 0.f || v.w > 0.f) {
            const int y  = t / (WI/4);
            const int x4 = (t - y * (WI/4)) * 4;
            const float vv[4] = {v.x, v.y, v.z, v.w};
            #pragma unroll
            for (int q = 0; q < 4; ++q) {
                if (vv[q] > 0.f) {
                    const int x = x4 + q;
                    atomicMax(&bb[0], (u32)(HI - y));
                    atomicMax(&bb[1], (u32)(y + 1));
                    atomicMax(&bb[2], (u32)(WI - x));
                    atomicMax(&bb[3], (u32)(x + 1));
                    const int i = (y + 7) >> 4;
                    const int j = (x + 7) >> 4;
                    if (((y & 15) != 8) && i < HF && ((x & 15) != 8) && j < WF)
                        ms[i*WF + j] = 1;
                }
            }
        }
    }

    // ---- completion protocol ----
    __shared__ int s_win;
    __threadfence();               // release: my stores/atomics visible at L2
    __syncthreads();               // all waves of this block fenced
    if (threadIdx.x == 0) {
        const u32 old = atomicAdd(&cnt[nm], 1u);
        s_win = (old == (u32)(SCAN_BX - 1)) ? 1 : 0;
    }
    __syncthreads();
    if (!s_win || threadIdx.x >= 64) return;

    // ---- weights body (first wave of the winning block; map complete) ----
    __threadfence();               // acquire: invalidate L1, read L2 data
    const int tid = threadIdx.x;   // 0..63

    const uint4 bbv = ((const uint4*)bbox)[nm];
    float bf0, bf1, bf2, bf3;
    if (bbv.y == 0u) {             // empty mask
        bf0 = bf1 = bf2 = bf3 = 0.f;
    } else {
        const int ymin = HI - (int)bbv.x, ymax = (int)bbv.y - 1;
        const int xmin = WI - (int)bbv.z, xmax = (int)bbv.w - 1;
        // dilate(+-7) + expand(+-1) + clip == +-8 clipped; /16 exact
        bf0 = (float)max(xmin - 8, 0) * 0.0625f;
        bf1 = (float)max(ymin - 8, 0) * 0.0625f;
        bf2 = (float)min(xmax + 8, WI - 1) * 0.0625f;
        bf3 = (float)min(ymax + 8, HI - 1) * 0.0625f;
    }
    if (tid == 0) {
        out[nm*4+0] = bf0 * (1.f/HF);
        out[nm*4+1] = bf1 * (1.f/HF);
        out[nm*4+2] = bf2 * (1.f/HF);
        out[nm*4+3] = bf3 * (1.f/HF);
    }

    // roi_masks crop (8x8 over masks_small)
    const int x1c = max((int)floorf(bf0), 0);
    const int y1c = max((int)floorf(bf1), 0);
    const int x2c = min((int)floorf(bf2), WF - 1);
    const int y2c = min((int)floorf(bf3), HF - 1);
    const int h = y2c - y1c + 1;
    const int w = x2c - x1c + 1;
    const int r = tid >> 3, s = tid & 7;
    const int yi = y1c + (r * h) / R_;
    const int xi = x1c + (s * w) / R_;
    const float cv = (float)ms[yi*WF + xi];
    const float m = __any(cv > 0.f) ? cv : 1.f;   // first wave only: wave-wide OR
    out[NM*4 + nm*64 + tid] = m;

    // bilinear sample positions/weights (shared across all channels);
    // crop-mask value folded into the weights: emb = sum((w_i*m) * v_i)
    const float bw = fmaxf(bf2 - bf0, 1.f) * (1.f / R_);
    const float bh = fmaxf(bf3 - bf1, 1.f) * (1.f / R_);
    float py = bf1 + ((float)r + 0.5f) * bh;
    float px = bf0 + ((float)s + 0.5f) * bw;
    py = fminf(fmaxf(py, 0.f), (float)(HF - 1));
    px = fminf(fmaxf(px, 0.f), (float)(WF - 1));
    const int y0 = (int)floorf(py);
    const int x0 = (int)floorf(px);
    const int y1i = min(y0 + 1, HF - 1);
    const int x1i = min(x0 + 1, WF - 1);
    const float ly = py - (float)y0, lx = px - (float)x0;
    const float hy = 1.f - ly,       hx = 1.f - lx;
    wm4[nm*64 + tid] = make_float4(hy*hx*m, hy*lx*m, ly*hx*m, ly*lx*m);
    a4[nm*64 + tid] = make_ushort4((unsigned short)(y0*WF + x0),
                                   (unsigned short)(y0*WF + x1i),
                                   (unsigned short)(y1i*WF + x0),
                                   (unsigned short)(y1i*WF + x1i));
}

// Phase 2: roi-align gather. Block = (n, 4-channel chunk): stage
// feat[n, c0:c0+4, :] in LDS once (each feat byte read from HBM exactly
// once across the grid), then all 64 masks gather from LDS.
// Thread map: wave = m_sub (4 masks/iteration), lane = (c_l, pos4);
// each thread emits 4 consecutive positions as ONE float4 -> every wave
// store is 1KB contiguous (4 channels x 64 floats).  (byte-identical to r8)
__global__ __launch_bounds__(256) void roi_gather_kernel(
        const float* __restrict__ feat,
        const float4* __restrict__ wm4,
        const ushort4* __restrict__ a4,
        float* __restrict__ out) {
    __shared__ float sfeat[4][HWF + 4];   // +4 pad: 16B-aligned rows, bank-skewed
    const int n  = blockIdx.y;
    const int c0 = blockIdx.x * 4;
    const int tid = threadIdx.x;

    // stage 4 channel planes (2304 float4 total, 9 per thread, coalesced, NT)
    const f32x4* fsrc = (const f32x4*)(feat + ((size_t)(n * C_ + c0)) * HWF);
    #pragma unroll
    for (int i = 0; i < 9; ++i) {
        const int idx = i * 256 + tid;        // 0..2303 float4s
        const int row = idx / (HWF/4);        // /576
        const int col = idx - row * (HWF/4);
        *(f32x4*)&sfeat[row][col * 4] = __builtin_nontemporal_load(fsrc + idx);
    }
    __syncthreads();

    const int m_sub = tid >> 6;          // wave id: 0..3
    const int c_l   = (tid >> 4) & 3;    // channel within chunk
    const int pos4  = tid & 15;          // float4 position group
    const float* srow = sfeat[c_l];
    float* emb = out + NM*4 + NM*64;

    #pragma unroll 4
    for (int mb = 0; mb < M_; mb += 4) {
        const int nm = n * M_ + mb + m_sub;
        const int tb = nm * 64 + pos4 * 4;
        const float4  w0 = wm4[tb+0], w1 = wm4[tb+1], w2 = wm4[tb+2], w3 = wm4[tb+3];
        const ushort4 A0 = a4[tb+0],  A1 = a4[tb+1],  A2 = a4[tb+2],  A3 = a4[tb+3];
        float4 r;
        r.x = w0.x*srow[A0.x] + w0.y*srow[A0.y] + w0.z*srow[A0.z] + w0.w*srow[A0.w];
        r.y = w1.x*srow[A1.x] + w1.y*srow[A1.y] + w1.z*srow[A1.z] + w1.w*srow[A1.w];
        r.z = w2.x*srow[A2.x] + w2.y*srow[A2.y] + w2.z*srow[A2.z] + w2.w*srow[A2.w];
        r.w = w3.x*srow[A3.x] + w3.y*srow[A3.y] + w3.z*srow[A3.z] + w3.w*srow[A3.w];
        __builtin_nontemporal_store(*(const f32x4*)&r,
            (f32x4*)&emb[((size_t)nm * C_ + c0 + c_l) * 64 + pos4 * 4]);
    }
}

extern "C" void kernel_launch(void* const* d_in, const int* in_sizes, int n_in,
                              void* d_out, int out_size, void* d_ws, size_t ws_size,
                              hipStream_t stream) {
    const float* feat  = (const float*)d_in[0];   // (4,768,48,48)
    const float* masks = (const float*)d_in[1];   // (4,64,768,768)
    float* out = (float*)d_out;

    char* ws = (char*)d_ws;
    u32* bbox             = (u32*)(ws + WS_BBOX_OFF);
    unsigned char* msmall = (unsigned char*)(ws + WS_MS_OFF);
    u32* cnt              = (u32*)(ws + WS_CNT_OFF);
    float4*  wm4          = (float4*)(ws + WS_W4_OFF);
    ushort4* a4           = (ushort4*)(ws + WS_A4_OFF);

    // init: bbox (all-atomicMax encoding => zeros) + msmall + counters, one memset
    hipMemsetAsync(ws, 0, WS_ZERO_BYTES, stream);

    // phase 1: stream masks + per-map fused weights (boxes/roi_masks/tables)
    dim3 g1(SCAN_BX, NM);   // (36, 256)
    scan_weights_kernel<<<g1, 256, 0, stream>>>(
        (const f32x4*)masks, bbox, msmall, cnt, wm4, a4, out);

    // phase 2: LDS-staged roi-align gather -> emb (float4 wave-contiguous stores)
    dim3 g2(C_/4, N_);      // (192, 4)
    roi_gather_kernel<<<g2, 256, 0, stream>>>(feat, wm4, a4, out);
}

// Round 12
// 134.117 us; speedup vs baseline: 10.2140x; 10.2140x over previous
//
#include <hip/hip_runtime.h>
#include <hip/hip_bf16.h>

// Problem constants (fixed by setup_inputs)
#define N_ 4
#define M_ 64
#define C_ 768
#define HF 48
#define WF 48
#define HWF (HF*WF)   // 2304
#define HI 768
#define WI 768
#define R_ 8
#define NM (N_*M_)

// ws layout:
//   [0)        uint bbox[NM][4]  (ymin'=max(768-y), ymax'=max(y+1),
//                                 xmin'=max(768-x), xmax'=max(x+1); empty <=> ymax'==0)
//   [4096)     uint8 masks_small[NM][48*48]
//   [1<<20)    float4  wm4[NM*64]  bilinear weights * crop-mask   256 KB
//   [+256K)    ushort4 a4[NM*64]   corner hw-indices              128 KB
// One hipMemsetAsync(0) over [0, 4096 + NM*2304) initializes bbox+msmall.
#define WS_BBOX_OFF   0
#define WS_MS_OFF     4096
#define MS_PER_MAP    (HF*WF)   // 2304
#define WS_ZERO_BYTES (WS_MS_OFF + NM*MS_PER_MAP)   // 593920
#define WS_W4_OFF     (1u<<20)
#define WS_A4_OFF     (WS_W4_OFF + NM*64*16)

#define VEC4_PER_MAP  (HI*WI/4)                       // 147456
#define SCAN_LPT      16                              // float4 NT loads/thread
#define SCAN_BX       (VEC4_PER_MAP/(256*SCAN_LPT))   // 36

typedef float f32x4 __attribute__((ext_vector_type(4)));
typedef unsigned int u32;

// Phase 1: stream the 604MB mask tensor once (r6/r8 known-good hot loop:
// nontemporal float4, LPT=16, interleaved test). Five variants (NT, batch,
// LPT8, cached, asm sc0/sc1/nt pipeline) all pin at ~5.4 TB/s => empirical
// read ceiling for this pattern. r11's per-block __threadfence fusion was
// a 10x regression (device-scope L2 wb/inv per block) — do NOT fuse with
// device fences; the kernel boundary is cheaper.
// window(15) < stride(16) => each nonzero pixel maps to at most one
// masks_small cell: i=(y+7)>>4, valid iff (y&15)!=8 && i<48.
__global__ void scan_masks_kernel(const f32x4* __restrict__ masks,
                                  u32* __restrict__ bbox,
                                  unsigned char* __restrict__ msmall) {
    const int nm = blockIdx.y;
    const size_t map_off = (size_t)nm * VEC4_PER_MAP;
    const int chunk = blockIdx.x * (256 * SCAN_LPT);
    u32* bb = bbox + nm * 4;
    unsigned char* ms = msmall + nm * MS_PER_MAP;

    #pragma unroll
    for (int k = 0; k < SCAN_LPT; ++k) {
        const int t = chunk + k * 256 + threadIdx.x;
        const f32x4 v = __builtin_nontemporal_load(masks + map_off + t);
        if (v.x > 0.f || v.y > 0.f || v.z > 0.f || v.w > 0.f) {
            const int y  = t / (WI/4);
            const int x4 = (t - y * (WI/4)) * 4;
            const float vv[4] = {v.x, v.y, v.z, v.w};
            #pragma unroll
            for (int q = 0; q < 4; ++q) {
                if (vv[q] > 0.f) {
                    const int x = x4 + q;
                    atomicMax(&bb[0], (u32)(HI - y));
                    atomicMax(&bb[1], (u32)(y + 1));
                    atomicMax(&bb[2], (u32)(WI - x));
                    atomicMax(&bb[3], (u32)(x + 1));
                    const int i = (y + 7) >> 4;
                    const int j = (x + 7) >> 4;
                    if (((y & 15) != 8) && i < HF && ((x & 15) != 8) && j < WF)
                        ms[i*WF + j] = 1;
                }
            }
        }
    }
}

// Phase 2a: per nm — boxes (out0), roi_masks crop (out1), and the
// (weights*mask, corner-index) table for the gather kernel.
__global__ void weights_kernel(const u32* __restrict__ bbox,
                               const unsigned char* __restrict__ msmall,
                               float4* __restrict__ wm4,
                               ushort4* __restrict__ a4,
                               float* __restrict__ out) {
    const int nm = blockIdx.x;
    const int tid = threadIdx.x;   // 0..63

    const uint4 bb = ((const uint4*)bbox)[nm];
    float bf0, bf1, bf2, bf3;
    if (bb.y == 0u) {            // empty mask
        bf0 = bf1 = bf2 = bf3 = 0.f;
    } else {
        const int ymin = HI - (int)bb.x, ymax = (int)bb.y - 1;
        const int xmin = WI - (int)bb.z, xmax = (int)bb.w - 1;
        // dilate(+-7) + expand(+-1) + clip == +-8 clipped; /16 exact
        bf0 = (float)max(xmin - 8, 0) * 0.0625f;
        bf1 = (float)max(ymin - 8, 0) * 0.0625f;
        bf2 = (float)min(xmax + 8, WI - 1) * 0.0625f;
        bf3 = (float)min(ymax + 8, HI - 1) * 0.0625f;
    }
    if (tid == 0) {
        out[nm*4+0] = bf0 * (1.f/HF);
        out[nm*4+1] = bf1 * (1.f/HF);
        out[nm*4+2] = bf2 * (1.f/HF);
        out[nm*4+3] = bf3 * (1.f/HF);
    }

    // roi_masks crop (8x8 over masks_small)
    const int x1c = max((int)floorf(bf0), 0);
    const int y1c = max((int)floorf(bf1), 0);
    const int x2c = min((int)floorf(bf2), WF - 1);
    const int y2c = min((int)floorf(bf3), HF - 1);
    const int h = y2c - y1c + 1;
    const int w = x2c - x1c + 1;
    const int r = tid >> 3, s = tid & 7;
    const int yi = y1c + (r * h) / R_;
    const int xi = x1c + (s * w) / R_;
    const float cv = (float)msmall[nm*MS_PER_MAP + yi*WF + xi];
    const float m = __any(cv > 0.f) ? cv : 1.f;
    out[NM*4 + nm*64 + tid] = m;

    // bilinear sample positions/weights (shared across all channels);
    // crop-mask value folded into the weights: emb = sum((w_i*m) * v_i)
    const float bw = fmaxf(bf2 - bf0, 1.f) * (1.f / R_);
    const float bh = fmaxf(bf3 - bf1, 1.f) * (1.f / R_);
    float py = bf1 + ((float)r + 0.5f) * bh;
    float px = bf0 + ((float)s + 0.5f) * bw;
    py = fminf(fmaxf(py, 0.f), (float)(HF - 1));
    px = fminf(fmaxf(px, 0.f), (float)(WF - 1));
    const int y0 = (int)floorf(py);
    const int x0 = (int)floorf(px);
    const int y1i = min(y0 + 1, HF - 1);
    const int x1i = min(x0 + 1, WF - 1);
    const float ly = py - (float)y0, lx = px - (float)x0;
    const float hy = 1.f - ly,       hx = 1.f - lx;
    wm4[nm*64 + tid] = make_float4(hy*hx*m, hy*lx*m, ly*hx*m, ly*lx*m);
    a4[nm*64 + tid] = make_ushort4((unsigned short)(y0*WF + x0),
                                   (unsigned short)(y0*WF + x1i),
                                   (unsigned short)(y1i*WF + x0),
                                   (unsigned short)(y1i*WF + x1i));
}

// Phase 2b: roi-align gather. Block = (n, 4-channel chunk): stage
// feat[n, c0:c0+4, :] in LDS once (each feat byte read from HBM exactly
// once across the grid), then all 64 masks gather from LDS.
// Thread map: wave = m_sub (4 masks/iteration), lane = (c_l, pos4);
// each thread emits 4 consecutive positions as ONE float4 -> every wave
// store is 1KB contiguous (4 channels x 64 floats).
__global__ __launch_bounds__(256) void roi_gather_kernel(
        const float* __restrict__ feat,
        const float4* __restrict__ wm4,
        const ushort4* __restrict__ a4,
        float* __restrict__ out) {
    __shared__ float sfeat[4][HWF + 4];   // +4 pad: 16B-aligned rows, bank-skewed
    const int n  = blockIdx.y;
    const int c0 = blockIdx.x * 4;
    const int tid = threadIdx.x;

    // stage 4 channel planes (2304 float4 total, 9 per thread, coalesced, NT)
    const f32x4* fsrc = (const f32x4*)(feat + ((size_t)(n * C_ + c0)) * HWF);
    #pragma unroll
    for (int i = 0; i < 9; ++i) {
        const int idx = i * 256 + tid;        // 0..2303 float4s
        const int row = idx / (HWF/4);        // /576
        const int col = idx - row * (HWF/4);
        *(f32x4*)&sfeat[row][col * 4] = __builtin_nontemporal_load(fsrc + idx);
    }
    __syncthreads();

    const int m_sub = tid >> 6;          // wave id: 0..3
    const int c_l   = (tid >> 4) & 3;    // channel within chunk
    const int pos4  = tid & 15;          // float4 position group
    const float* srow = sfeat[c_l];
    float* emb = out + NM*4 + NM*64;

    #pragma unroll 4
    for (int mb = 0; mb < M_; mb += 4) {
        const int nm = n * M_ + mb + m_sub;
        const int tb = nm * 64 + pos4 * 4;
        const float4  w0 = wm4[tb+0], w1 = wm4[tb+1], w2 = wm4[tb+2], w3 = wm4[tb+3];
        const ushort4 A0 = a4[tb+0],  A1 = a4[tb+1],  A2 = a4[tb+2],  A3 = a4[tb+3];
        float4 r;
        r.x = w0.x*srow[A0.x] + w0.y*srow[A0.y] + w0.z*srow[A0.z] + w0.w*srow[A0.w];
        r.y = w1.x*srow[A1.x] + w1.y*srow[A1.y] + w1.z*srow[A1.z] + w1.w*srow[A1.w];
        r.z = w2.x*srow[A2.x] + w2.y*srow[A2.y] + w2.z*srow[A2.z] + w2.w*srow[A2.w];
        r.w = w3.x*srow[A3.x] + w3.y*srow[A3.y] + w3.z*srow[A3.z] + w3.w*srow[A3.w];
        __builtin_nontemporal_store(*(const f32x4*)&r,
            (f32x4*)&emb[((size_t)nm * C_ + c0 + c_l) * 64 + pos4 * 4]);
    }
}

extern "C" void kernel_launch(void* const* d_in, const int* in_sizes, int n_in,
                              void* d_out, int out_size, void* d_ws, size_t ws_size,
                              hipStream_t stream) {
    const float* feat  = (const float*)d_in[0];   // (4,768,48,48)
    const float* masks = (const float*)d_in[1];   // (4,64,768,768)
    float* out = (float*)d_out;

    char* ws = (char*)d_ws;
    u32* bbox             = (u32*)(ws + WS_BBOX_OFF);
    unsigned char* msmall = (unsigned char*)(ws + WS_MS_OFF);
    float4*  wm4          = (float4*)(ws + WS_W4_OFF);
    ushort4* a4           = (ushort4*)(ws + WS_A4_OFF);

    // init: bbox (all-atomicMax encoding => zeros) + msmall zeros, one memset
    hipMemsetAsync(ws, 0, WS_ZERO_BYTES, stream);

    // phase 1: stream masks (NT, LPT16 — known-good config)
    dim3 g1(SCAN_BX, NM);   // (36, 256)
    scan_masks_kernel<<<g1, 256, 0, stream>>>((const f32x4*)masks, bbox, msmall);

    // phase 2a: boxes + roi_masks + weight/index table
    weights_kernel<<<NM, 64, 0, stream>>>(bbox, msmall, wm4, a4, out);

    // phase 2b: LDS-staged roi-align gather -> emb (float4 wave-contiguous stores)
    dim3 g2(C_/4, N_);      // (192, 4)
    roi_gather_kernel<<<g2, 256, 0, stream>>>(feat, wm4, a4, out);
}